// Round 7
// baseline (37.219 us; speedup 1.0000x reference)
//
#include <hip/hip_runtime.h>

#define BATCH     4096
#define NCTX      8
#define NK        6
#define VDIM      256
#define NWORDS    50000
#define NPAIRS    (BATCH * NK)              // 24576
#define CBLK      32                        // columns of O per score block
#define NBINS     ((NWORDS + CBLK - 1) / CBLK)   // 1563
#define CAP       64                        // pairs per bin (mean 15.7)
#define TSTRIDE   (VDIM + 2)                // 258: write-side ~2-way (free), read contiguous

#define X_ELEMS   (BATCH * VDIM)

// ---------------------------------------------------------------------------
// Kernel 1: x[b,:] = D[doc[b],:] + sum_c W[ctx[b,c],:]  -> ws. One wave per
// batch element, float4/lane. Block 0 also zeroes bin counters.
// ---------------------------------------------------------------------------
__global__ __launch_bounds__(256)
void DM_42417097016803_xbuild(const int* __restrict__ ctx,
                              const int* __restrict__ doc,
                              const float* __restrict__ D,
                              const float* __restrict__ W,
                              float* __restrict__ x,
                              int* __restrict__ counts)
{
    if (blockIdx.x == 0) {
        for (int j = threadIdx.x; j < NBINS; j += 256) counts[j] = 0;
    }

    const int wave = threadIdx.x >> 6;
    const int lane = threadIdx.x & 63;
    const int b    = blockIdx.x * 4 + wave;

    const float4* __restrict__ D4 = reinterpret_cast<const float4*>(D);
    const float4* __restrict__ W4 = reinterpret_cast<const float4*>(W);
    float4* __restrict__       x4 = reinterpret_cast<float4*>(x);

    const int docid = doc[b];
    float4 v = D4[(size_t)docid * 64 + lane];
#pragma unroll
    for (int c = 0; c < NCTX; ++c) {
        const int id = ctx[b * NCTX + c];
        const float4 w = W4[(size_t)id * 64 + lane];
        v.x += w.x; v.y += w.y; v.z += w.z; v.w += w.w;
    }
    x4[(size_t)b * 64 + lane] = v;
}

// ---------------------------------------------------------------------------
// Kernel 2: bin the 24576 (b,k) pairs by column-block of their target id.
// Stores packed (pair_idx << 5) | (col & 31).
// ---------------------------------------------------------------------------
__global__ __launch_bounds__(256)
void DM_42417097016803_bin(const int* __restrict__ tgt,
                           int* __restrict__ counts,
                           int* __restrict__ bins)
{
    const int i = blockIdx.x * 256 + threadIdx.x;   // exactly NPAIRS threads
    const int c = tgt[i];
    const int bin = c >> 5;                          // CBLK = 32
    const int pos = atomicAdd(&counts[bin], 1);
    if (pos < CAP) bins[bin * CAP + pos] = (i << 5) | (c & (CBLK - 1));
}

// ---------------------------------------------------------------------------
// Kernel 3: block bid owns O columns [bid*32, bid*32+32). ALL loads issued
// before the barrier: chunk-A pair metadata + x-rows, the 8 tile float4s,
// chunk-B metadata + x-rows. After one __syncthreads the pair phase is pure
// LDS + VALU. Covers np<=32 in registers; residual loop for the ~1e-4 tail.
// ---------------------------------------------------------------------------
__global__ __launch_bounds__(256, 4)
void DM_42417097016803_score(const int* __restrict__ counts,
                             const int* __restrict__ bins,
                             const float* __restrict__ x,
                             const float* __restrict__ O,
                             float* __restrict__ out)
{
    __shared__ float tile[CBLK][TSTRIDE];   // 33 KB

    const int tid  = threadIdx.x;
    const int bid  = blockIdx.x;
    const int c0   = bid * CBLK;
    const int ncols = (NWORDS - c0 < CBLK) ? (NWORDS - c0) : CBLK;
    const int wave = tid >> 6;
    const int lane = tid & 63;

    int np = counts[bid];                    // small, L2-resident
    if (np > CAP) np = CAP;

    const float4* __restrict__ x4 = reinterpret_cast<const float4*>(x);
    const int* __restrict__ mybins = &bins[bid * CAP];

    // --- chunk A: pairs wave+4j (covers np<=16): metadata + x-row loads ---
    int    pkA[4]; float4 xvA[4]; int nA = 0;
#pragma unroll
    for (int j = 0; j < 4; ++j) {
        const int p = wave + 4 * j;
        if (p < np) {
            const int pk = mybins[p];
            pkA[j] = pk;
            xvA[j] = x4[(size_t)((unsigned)(pk >> 5) / NK) * 64 + lane];
            nA = j + 1;
        }
    }

    // --- tile loads (independent; in flight with the x gathers) ---
    const int c4  = tid & 7;
    const int row = tid >> 3;
    const bool ld = (c4 * 4 < ncols);        // last block: ncols=16 (mult of 4)
    float4 r[8];
    if (ld) {
#pragma unroll
        for (int rb = 0; rb < 8; ++rb)
            r[rb] = *reinterpret_cast<const float4*>(
                &O[(size_t)(rb * 32 + row) * NWORDS + c0 + c4 * 4]);
    }

    // --- chunk B: pairs 16+wave+4j (covers np<=32) ---
    int    pkB[4]; float4 xvB[4]; int nB = 0;
#pragma unroll
    for (int j = 0; j < 4; ++j) {
        const int p = 16 + wave + 4 * j;
        if (p < np) {
            const int pk = mybins[p];
            pkB[j] = pk;
            xvB[j] = x4[(size_t)((unsigned)(pk >> 5) / NK) * 64 + lane];
            nB = j + 1;
        }
    }

    // --- tile regs -> LDS (transposed) ---
    if (ld) {
#pragma unroll
        for (int rb = 0; rb < 8; ++rb) {
            const int t = rb * 32 + row;
            tile[c4 * 4 + 0][t] = r[rb].x;
            tile[c4 * 4 + 1][t] = r[rb].y;
            tile[c4 * 4 + 2][t] = r[rb].z;
            tile[c4 * 4 + 3][t] = r[rb].w;
        }
    }
    __syncthreads();

    // --- pair phase: pure LDS + VALU ---
#pragma unroll
    for (int j = 0; j < 4; ++j) {
        if (j < nA) {
            const int i = pkA[j] >> 5;
            const int c = pkA[j] & (CBLK - 1);
            const float4 ov = *reinterpret_cast<const float4*>(&tile[c][lane * 4]);
            float d = xvA[j].x * ov.x + xvA[j].y * ov.y
                    + xvA[j].z * ov.z + xvA[j].w * ov.w;
#pragma unroll
            for (int off = 32; off >= 1; off >>= 1)
                d += __shfl_down(d, off, 64);
            if (lane == 0) out[i] = d;
        }
    }
#pragma unroll
    for (int j = 0; j < 4; ++j) {
        if (j < nB) {
            const int i = pkB[j] >> 5;
            const int c = pkB[j] & (CBLK - 1);
            const float4 ov = *reinterpret_cast<const float4*>(&tile[c][lane * 4]);
            float d = xvB[j].x * ov.x + xvB[j].y * ov.y
                    + xvB[j].z * ov.z + xvB[j].w * ov.w;
#pragma unroll
            for (int off = 32; off >= 1; off >>= 1)
                d += __shfl_down(d, off, 64);
            if (lane == 0) out[i] = d;
        }
    }

    // --- residual (np > 32; ~1e-4 of bins) ---
    for (int p = 32 + wave; p < np; p += 4) {
        const int pk = mybins[p];
        const int i = pk >> 5;
        const int c = pk & (CBLK - 1);
        const float4 xv = x4[(size_t)((unsigned)i / NK) * 64 + lane];
        const float4 ov = *reinterpret_cast<const float4*>(&tile[c][lane * 4]);
        float d = xv.x * ov.x + xv.y * ov.y + xv.z * ov.z + xv.w * ov.w;
#pragma unroll
        for (int off = 32; off >= 1; off >>= 1)
            d += __shfl_down(d, off, 64);
        if (lane == 0) out[i] = d;
    }
}

// ---------------------------------------------------------------------------
// Fallback (direct strided-O gather) in case ws is too small.
// ---------------------------------------------------------------------------
__global__ __launch_bounds__(256)
void DM_42417097016803_fallback(const int* __restrict__ ctx,
                                const int* __restrict__ doc,
                                const int* __restrict__ tid,
                                const float* __restrict__ D,
                                const float* __restrict__ W,
                                const float* __restrict__ O,
                                float* __restrict__ out)
{
    const int b = blockIdx.x;
    const int t = threadIdx.x;

    __shared__ int s_idx[NCTX + NK + 1];
    if (t < NCTX)            s_idx[t] = ctx[b * NCTX + t];
    else if (t < NCTX + NK)  s_idx[t] = tid[b * NK + (t - NCTX)];
    else if (t == NCTX + NK) s_idx[t] = doc[b];
    __syncthreads();

    const int docid = s_idx[NCTX + NK];
    float x = D[(size_t)docid * VDIM + t];
#pragma unroll
    for (int c = 0; c < NCTX; ++c)
        x += W[(size_t)s_idx[c] * VDIM + t];

    float p[NK];
#pragma unroll
    for (int k = 0; k < NK; ++k)
        p[k] = x * O[(size_t)t * NWORDS + s_idx[NCTX + k]];

#pragma unroll
    for (int k = 0; k < NK; ++k) {
#pragma unroll
        for (int off = 32; off >= 1; off >>= 1)
            p[k] += __shfl_down(p[k], off, 64);
    }

    __shared__ float s_part[4][NK];
    const int wave = t >> 6;
    const int lane = t & 63;
    if (lane == 0) {
#pragma unroll
        for (int k = 0; k < NK; ++k) s_part[wave][k] = p[k];
    }
    __syncthreads();

    if (t < NK)
        out[b * NK + t] = s_part[0][t] + s_part[1][t] + s_part[2][t] + s_part[3][t];
}

extern "C" void kernel_launch(void* const* d_in, const int* in_sizes, int n_in,
                              void* d_out, int out_size, void* d_ws, size_t ws_size,
                              hipStream_t stream)
{
    const int*   ctx = (const int*)d_in[0];   // (4096, 8)
    const int*   doc = (const int*)d_in[1];   // (4096,)
    const int*   tid = (const int*)d_in[2];   // (4096, 6)
    const float* D   = (const float*)d_in[3]; // (100000, 256)
    const float* W   = (const float*)d_in[4]; // (50000, 256)
    const float* O   = (const float*)d_in[5]; // (256, 50000)
    float*       out = (float*)d_out;         // (4096, 6)

    const size_t x_bytes     = (size_t)X_ELEMS * sizeof(float);       // 4 MB
    const size_t count_bytes = (size_t)NBINS * sizeof(int);
    const size_t bin_bytes   = (size_t)NBINS * CAP * sizeof(int);

    if (ws_size >= x_bytes + count_bytes + bin_bytes) {
        float* x      = (float*)d_ws;
        int*   counts = (int*)((char*)d_ws + x_bytes);
        int*   bins   = counts + NBINS;

        DM_42417097016803_xbuild<<<BATCH / 4, 256, 0, stream>>>(
            ctx, doc, D, W, x, counts);
        DM_42417097016803_bin<<<NPAIRS / 256, 256, 0, stream>>>(
            tid, counts, bins);
        DM_42417097016803_score<<<NBINS, 256, 0, stream>>>(
            counts, bins, x, O, out);
    } else {
        DM_42417097016803_fallback<<<BATCH, 256, 0, stream>>>(
            ctx, doc, tid, D, W, O, out);
    }
}